// Round 9
// baseline (98.218 us; speedup 1.0000x reference)
//
#include <hip/hip_runtime.h>
#include <hip/hip_bf16.h>
#include <math.h>

#define BATCH 32
#define WLEN  2048

typedef __attribute__((ext_vector_type(8))) short short8;
typedef __attribute__((ext_vector_type(4))) short short4v;
typedef __attribute__((ext_vector_type(4))) float floatx4;

// async global->LDS DMA, 16 B per lane; lds base must be wave-uniform.
#define GLOAD_LDS16(g, l)                                                     \
  __builtin_amdgcn_global_load_lds(                                           \
      (const __attribute__((address_space(1))) unsigned int*)(g),             \
      (__attribute__((address_space(3))) unsigned int*)(l), 16, 0, 0)

__device__ inline short f2bf(float f) {
  unsigned u = __float_as_uint(f);
  unsigned r = (u + 0x7fffu + ((u >> 16) & 1u)) >> 16;
  return (short)r;
}

// ---------------------------------------------------------------------------
// fused prep: blocks 0..11 pack w1 -> wp1[k][ig8][o128][8]
//             blocks 12..59 pack w2 -> wp2[k][ig16][o256][8]
//             blocks 60..315 routing1 partials racc1[b*8+j]
// ---------------------------------------------------------------------------
__global__ __launch_bounds__(256) void fused_prep(
    const float* __restrict__ w1, const float* __restrict__ w2,
    const float* __restrict__ x, const float* __restrict__ fcw1,
    short* __restrict__ wp1, short* __restrict__ wp2,
    float* __restrict__ racc1) {
  const int blk = blockIdx.x;
  const int tid = threadIdx.x;
  if (blk < 12) {
    int iw = blk * 256 + tid;          // (k, ig, o) over 3*8*128
    int o = iw & 127;
    int t = iw >> 7;
    int ig = t & 7;
    int k = t >> 3;
    short8 v;
#pragma unroll
    for (int e = 0; e < 8; ++e) v[e] = f2bf(w1[(o * 64 + ig * 8 + e) * 3 + k]);
    *(short8*)(wp1 + (size_t)iw * 8) = v;
  } else if (blk < 60) {
    int iw = (blk - 12) * 256 + tid;   // (k, ig, o) over 3*16*256
    int o = iw & 255;
    int t = iw >> 8;
    int ig = t & 15;
    int k = t >> 4;
    short8 v;
#pragma unroll
    for (int e = 0; e < 8; ++e) v[e] = f2bf(w2[(o * 128 + ig * 8 + e) * 3 + k]);
    *(short8*)(wp2 + (size_t)iw * 8) = v;
  } else {
    int t = blk - 60;
    int j = t & 7, b = t >> 3;
    const float4* xb = (const float4*)(x + ((size_t)b * 64 + j * 8) * WLEN);
    float sum = 0.f;
    for (int idx = tid; idx < 8 * 512; idx += 256) {
      int c = idx >> 9;
      float4 v = xb[idx];
      sum += (v.x + v.y + v.z + v.w) * fcw1[j * 8 + c];
    }
    __shared__ float red[256];
    red[tid] = sum;
    __syncthreads();
    for (int s = 128; s > 0; s >>= 1) {
      if (tid < s) red[tid] += red[tid + s];
      __syncthreads();
    }
    if (tid == 0) racc1[b * 8 + j] = red[0];
  }
}

// ---------------------------------------------------------------------------
// conv1: x fp32 (B,64,W) -> y1p bf16 [b][o/8][w][8], + routing2 partials.
// 512 threads (8 waves), tile 128o x 128w; wave = 64o x 32w (4ms x 2ns).
// Weights (48KB) LDS-resident via global_load_lds. grid (16,32).
// y1 stores: kg pairs merged via shfl -> 16B/lane granule-dense writes.
// ---------------------------------------------------------------------------
__global__ __launch_bounds__(512, 4) void conv1_mfma(
    const float* __restrict__ x, const short* __restrict__ wp1,
    const float* __restrict__ bias, const float* __restrict__ g,
    const float* __restrict__ be, const float* __restrict__ rm,
    const float* __restrict__ rv, const float* __restrict__ racc1,
    const float* __restrict__ fcb, const float* __restrict__ fcw2,
    short* __restrict__ y1p, float* __restrict__ racc2) {
  const int b = blockIdx.y;
  const int w0 = blockIdx.x * 128;
  const int tid = threadIdx.x;
  const int wave = tid >> 6, lane = tid & 63;
  const int ln = lane & 15, kg = lane >> 4;
  const int oh = wave & 1, wq = wave >> 1;

  __shared__ short wl[3 * 8 * 128 * 8];  // 48 KB, [k][ig][o][e]
  __shared__ short xs[8 * 130 * 8];      // 16.6 KB, [ig][p][e]
  __shared__ float red[512];             // 2 KB

  // stage weights via async DMA: 3072 16B items, 6 per thread
#pragma unroll
  for (int c = 0; c < 6; ++c) {
    const int ib = c * 512 + wave * 64;  // wave-uniform item base
    GLOAD_LDS16(wp1 + (size_t)(ib + lane) * 8, wl + (size_t)ib * 8);
  }

  // stage x tile (fp32 -> bf16), halo of 1
  const float* xb = x + (size_t)b * 64 * WLEN;
  for (int idx = tid; idx < 8 * 130; idx += 512) {
    int ig = idx / 130;
    int p = idx - ig * 130;
    int w = w0 - 1 + p;
    short8 v = {0, 0, 0, 0, 0, 0, 0, 0};
    if ((unsigned)w < (unsigned)WLEN) {
      const float* src = xb + (size_t)(ig * 8) * WLEN + w;
#pragma unroll
      for (int e = 0; e < 8; ++e) v[e] = f2bf(src[(size_t)e * WLEN]);
    }
    *(short8*)(xs + idx * 8) = v;
  }
  __syncthreads();

  floatx4 acc[4][2];
#pragma unroll
  for (int ms = 0; ms < 4; ++ms)
#pragma unroll
    for (int ns = 0; ns < 2; ++ns) acc[ms][ns] = (floatx4){0.f, 0.f, 0.f, 0.f};

#pragma unroll
  for (int q = 0; q < 2; ++q) {
#pragma unroll
    for (int k = 0; k < 3; ++k) {
      short8 af[4], bf[2];
      const short* wk = wl + ((size_t)(k * 8 + q * 4 + kg) * 128 + oh * 64 + ln) * 8;
#pragma unroll
      for (int ms = 0; ms < 4; ++ms)
        af[ms] = *(const short8*)(wk + (size_t)ms * 16 * 8);
#pragma unroll
      for (int ns = 0; ns < 2; ++ns)
        bf[ns] = *(const short8*)(
            xs + ((q * 4 + kg) * 130 + wq * 32 + ns * 16 + ln + k) * 8);
#pragma unroll
      for (int ms = 0; ms < 4; ++ms)
#pragma unroll
        for (int ns = 0; ns < 2; ++ns)
          acc[ms][ns] = __builtin_amdgcn_mfma_f32_16x16x32_bf16(
              af[ms], bf[ns], acc[ms][ns], 0, 0, 0);
    }
  }

  // r1
  float zs = 0.f;
#pragma unroll
  for (int qq = 0; qq < 8; ++qq) zs += racc1[b * 8 + qq];
  float z = zs * (1.f / (float)WLEN) + fcb[0];
  float r1v = 1.f / (1.f + expf(-z));

  float rsum2 = 0.f;
#pragma unroll
  for (int ms = 0; ms < 4; ++ms) {
    const int o0 = oh * 64 + ms * 16 + kg * 4;
    float a_[4], c_[4], fw[4];
#pragma unroll
    for (int rr = 0; rr < 4; ++rr) {
      int o = o0 + rr;
      float s = g[o] * rsqrtf(rv[o] + 1e-5f);
      a_[rr] = r1v * s;
      c_[rr] = (r1v * bias[o] - rm[o]) * s + be[o];
      fw[rr] = fcw2[o];
    }
#pragma unroll
    for (int ns = 0; ns < 2; ++ns) {
      int w = w0 + wq * 32 + ns * 16 + ln;
      short pk[4];
#pragma unroll
      for (int rr = 0; rr < 4; ++rr) {
        float v = acc[ms][ns][rr] * a_[rr] + c_[rr];
        v = v >= 0.f ? v : 0.1f * v;
        rsum2 += v * fw[rr];
        pk[rr] = f2bf(v);
      }
      // pack 4 bf16 into 2 dwords; merge with kg^1 partner (o0 xor 4)
      unsigned u0 = (unsigned)(unsigned short)pk[0] |
                    ((unsigned)(unsigned short)pk[1] << 16);
      unsigned u1 = (unsigned)(unsigned short)pk[2] |
                    ((unsigned)(unsigned short)pk[3] << 16);
      unsigned p0 = __shfl_xor((int)u0, 16);
      unsigned p1 = __shfl_xor((int)u1, 16);
      if (!(kg & 1)) {
        int4 s8;
        s8.x = (int)u0; s8.y = (int)u1; s8.z = (int)p0; s8.w = (int)p1;
        // y1p layout [b][o/8][w][8]; o0 is a multiple of 8 here
        *(int4*)(y1p + ((size_t)(b * 16 + (o0 >> 3)) * WLEN + w) * 8) = s8;
      }
    }
  }
  red[tid] = rsum2;
  __syncthreads();
  for (int s = 256; s > 0; s >>= 1) {
    if (tid < s) red[tid] += red[tid + s];
    __syncthreads();
  }
  if (tid == 0) racc2[b * 16 + blockIdx.x] = red[0];
}

// ---------------------------------------------------------------------------
// conv2: y1p bf16 [b][ig16][w][8] -> out fp32 pooled (B,256,1024).
// 512 threads (8 waves), tile 256o x 128w; wave = 64o x 64w (4ms x 4ns).
// Weight chunks (16KB) double-buffered via global_load_lds. grid (16,32).
// UNCHANGED from R7/R8 (clean C2 measurement).
// ---------------------------------------------------------------------------
__global__ __launch_bounds__(512, 4) void conv2_mfma(
    const short* __restrict__ y1p, const short* __restrict__ wp2,
    const float* __restrict__ bias, const float* __restrict__ g,
    const float* __restrict__ be, const float* __restrict__ rm,
    const float* __restrict__ rv, const float* __restrict__ racc2,
    const float* __restrict__ fcb, float* __restrict__ out) {
  const int b = blockIdx.y;
  const int w0 = blockIdx.x * 128;
  const int tid = threadIdx.x;
  const int wave = tid >> 6, lane = tid & 63;
  const int ln = lane & 15, kg = lane >> 4;
  const int oq = wave & 3, wh = wave >> 2;

  __shared__ short xs[16 * 130 * 8];   // 33.3 KB
  __shared__ short wbuf[2][8192];      // 32 KB, chunk = [4ig][256o][8e]

  // issue weight chunk 0 DMA (1024 items, 2 per thread)
  {
    const int ib0 = wave * 64, ib1 = 512 + wave * 64;
    GLOAD_LDS16(wp2 + (size_t)(ib0 + lane) * 8, wbuf[0] + (size_t)ib0 * 8);
    GLOAD_LDS16(wp2 + (size_t)(ib1 + lane) * 8, wbuf[0] + (size_t)ib1 * 8);
  }

  // stage x tile
  const short* yb = y1p + (size_t)b * 16 * WLEN * 8;
  for (int idx = tid; idx < 16 * 130; idx += 512) {
    int ig = idx / 130;
    int p = idx - ig * 130;
    int w = w0 - 1 + p;
    short8 v = {0, 0, 0, 0, 0, 0, 0, 0};
    if ((unsigned)w < (unsigned)WLEN)
      v = *(const short8*)(yb + ((size_t)ig * WLEN + w) * 8);
    *(short8*)(xs + idx * 8) = v;
  }
  __syncthreads();

  floatx4 acc[4][4];
#pragma unroll
  for (int ms = 0; ms < 4; ++ms)
#pragma unroll
    for (int ns = 0; ns < 4; ++ns) acc[ms][ns] = (floatx4){0.f, 0.f, 0.f, 0.f};

#pragma unroll
  for (int c = 0; c < 12; ++c) {
    const int cur = c & 1;
    const int q = c / 3, k = c % 3;

    // issue next chunk's DMA before the MFMA cluster
    if (c < 11) {
      const int nq = (c + 1) / 3, nk = (c + 1) % 3;
      const short* src = wp2 + (size_t)(nk * 16 + nq * 4) * 256 * 8;
      const int ib0 = wave * 64, ib1 = 512 + wave * 64;
      GLOAD_LDS16(src + (size_t)(ib0 + lane) * 8, wbuf[cur ^ 1] + (size_t)ib0 * 8);
      GLOAD_LDS16(src + (size_t)(ib1 + lane) * 8, wbuf[cur ^ 1] + (size_t)ib1 * 8);
    }

    short8 af[4], bf[4];
#pragma unroll
    for (int ms = 0; ms < 4; ++ms)
      af[ms] = *(const short8*)(
          wbuf[cur] + (size_t)(kg * 256 + oq * 64 + ms * 16 + ln) * 8);
#pragma unroll
    for (int ns = 0; ns < 4; ++ns)
      bf[ns] = *(const short8*)(
          xs + ((q * 4 + kg) * 130 + wh * 64 + ns * 16 + ln + k) * 8);
#pragma unroll
    for (int ms = 0; ms < 4; ++ms)
#pragma unroll
      for (int ns = 0; ns < 4; ++ns)
        acc[ms][ns] = __builtin_amdgcn_mfma_f32_16x16x32_bf16(
            af[ms], bf[ns], acc[ms][ns], 0, 0, 0);

    __syncthreads();
  }

  // r2
  float zs = 0.f;
#pragma unroll
  for (int t = 0; t < 16; ++t) zs += racc2[b * 16 + t];
  float z = zs * (1.f / (float)WLEN) + fcb[0];
  float r2v = 1.f / (1.f + expf(-z));

#pragma unroll
  for (int ms = 0; ms < 4; ++ms) {
    const int o0 = oq * 64 + ms * 16 + kg * 4;
    float a_[4], c_[4];
#pragma unroll
    for (int rr = 0; rr < 4; ++rr) {
      int o = o0 + rr;
      float s = g[o] * rsqrtf(rv[o] + 1e-5f);
      a_[rr] = r2v * s;
      c_[rr] = (r2v * bias[o] - rm[o]) * s + be[o];
    }
#pragma unroll
    for (int np = 0; np < 2; ++np) {  // ns pairs (0,1), (2,3)
      float m0[4], m1[4];
#pragma unroll
      for (int half = 0; half < 2; ++half) {
        int ns = np * 2 + half;
#pragma unroll
        for (int rr = 0; rr < 4; ++rr) {
          float v = acc[ms][ns][rr] * a_[rr] + c_[rr];
          v = v >= 0.f ? v : 0.1f * v;
          float m = fmaxf(v, __shfl_xor(v, 1));
          if (half == 0) m0[rr] = m; else m1[rr] = m;
        }
      }
      const int pc = (w0 >> 1) + wh * 32 + np * 16 + ln;
#pragma unroll
      for (int rr = 0; rr < 4; ++rr) {
        int src = kg * 16 + ((ln & 7) << 1);
        float aa = __shfl(m0[rr], src);
        float bb = __shfl(m1[rr], src);
        float val = (ln < 8) ? aa : bb;
        out[((size_t)(b * 256 + o0 + rr)) * (WLEN / 2) + pc] = val;
      }
    }
  }
}

// ---------------------------------------------------------------------------
extern "C" void kernel_launch(void* const* d_in, const int* in_sizes, int n_in,
                              void* d_out, int out_size, void* d_ws, size_t ws_size,
                              hipStream_t stream) {
  const float* x    = (const float*)d_in[0];
  const float* w1   = (const float*)d_in[1];
  const float* b1   = (const float*)d_in[2];
  const float* fcw1 = (const float*)d_in[3];
  const float* fcb1 = (const float*)d_in[4];
  const float* g1   = (const float*)d_in[5];
  const float* be1  = (const float*)d_in[6];
  const float* rm1  = (const float*)d_in[7];
  const float* rv1  = (const float*)d_in[8];
  const float* w2   = (const float*)d_in[9];
  const float* b2   = (const float*)d_in[10];
  const float* fcw2 = (const float*)d_in[11];
  const float* fcb2 = (const float*)d_in[12];
  const float* g2   = (const float*)d_in[13];
  const float* be2  = (const float*)d_in[14];
  const float* rm2  = (const float*)d_in[15];
  const float* rv2  = (const float*)d_in[16];
  float* out = (float*)d_out;

  char* ws = (char*)d_ws;
  short* y1p   = (short*)ws;                          // 32*16*2048*8*2 = 16 MiB
  short* wp1   = (short*)(ws + (size_t)16 * 1024 * 1024);            // 48 KiB
  short* wp2   = (short*)(ws + (size_t)16 * 1024 * 1024 + 65536);    // 192 KiB
  float* racc1 = (float*)(ws + (size_t)16 * 1024 * 1024 + 327680);   // 256 f
  float* racc2 = racc1 + 256;                                        // 512 f

  fused_prep<<<316, 256, 0, stream>>>(w1, w2, x, fcw1, wp1, wp2, racc1);
  conv1_mfma<<<dim3(16, 32), 512, 0, stream>>>(
      x, wp1, b1, g1, be1, rm1, rv1, racc1, fcb1, fcw2, y1p, racc2);
  // PROBE: conv2 launched 3x (idempotent). C2 = (dur - R7_dur - 2f + dC1)/2.
  for (int rep = 0; rep < 3; ++rep) {
    conv2_mfma<<<dim3(16, 32), 512, 0, stream>>>(
        y1p, wp2, b2, g2, be2, rm2, rv2, racc2, fcb2, out);
  }
}

// Round 10
// 60.110 us; speedup vs baseline: 1.6340x; 1.6340x over previous
//
#include <hip/hip_runtime.h>
#include <hip/hip_bf16.h>
#include <math.h>

#define BATCH 32
#define WLEN  2048

typedef __attribute__((ext_vector_type(8))) short short8;
typedef __attribute__((ext_vector_type(4))) short short4v;
typedef __attribute__((ext_vector_type(4))) float floatx4;

__device__ inline short f2bf(float f) {
  unsigned u = __float_as_uint(f);
  unsigned r = (u + 0x7fffu + ((u >> 16) & 1u)) >> 16;
  return (short)r;
}

// ---------------------------------------------------------------------------
// fused prep: blocks 0..11 pack w1 -> wp1[k][ig8][o128][8]
//             blocks 12..59 pack w2 -> wp2[k][ig16][o256][8]
//             blocks 60..315 routing1 partials racc1[b*8+j]
// ---------------------------------------------------------------------------
__global__ __launch_bounds__(256) void fused_prep(
    const float* __restrict__ w1, const float* __restrict__ w2,
    const float* __restrict__ x, const float* __restrict__ fcw1,
    short* __restrict__ wp1, short* __restrict__ wp2,
    float* __restrict__ racc1) {
  const int blk = blockIdx.x;
  const int tid = threadIdx.x;
  if (blk < 12) {
    int iw = blk * 256 + tid;          // (k, ig, o) over 3*8*128
    int o = iw & 127;
    int t = iw >> 7;
    int ig = t & 7;
    int k = t >> 3;
    short8 v;
#pragma unroll
    for (int e = 0; e < 8; ++e) v[e] = f2bf(w1[(o * 64 + ig * 8 + e) * 3 + k]);
    *(short8*)(wp1 + (size_t)iw * 8) = v;
  } else if (blk < 60) {
    int iw = (blk - 12) * 256 + tid;   // (k, ig, o) over 3*16*256
    int o = iw & 255;
    int t = iw >> 8;
    int ig = t & 15;
    int k = t >> 4;
    short8 v;
#pragma unroll
    for (int e = 0; e < 8; ++e) v[e] = f2bf(w2[(o * 128 + ig * 8 + e) * 3 + k]);
    *(short8*)(wp2 + (size_t)iw * 8) = v;
  } else {
    int t = blk - 60;
    int j = t & 7, b = t >> 3;
    const float4* xb = (const float4*)(x + ((size_t)b * 64 + j * 8) * WLEN);
    float sum = 0.f;
    for (int idx = tid; idx < 8 * 512; idx += 256) {
      int c = idx >> 9;
      float4 v = xb[idx];
      sum += (v.x + v.y + v.z + v.w) * fcw1[j * 8 + c];
    }
    __shared__ float red[256];
    red[tid] = sum;
    __syncthreads();
    for (int s = 128; s > 0; s >>= 1) {
      if (tid < s) red[tid] += red[tid + s];
      __syncthreads();
    }
    if (tid == 0) racc1[b * 8 + j] = red[0];
  }
}

// ---------------------------------------------------------------------------
// conv1: x fp32 (B,64,W) -> y1p bf16 [b][o/8][w][8], + routing2 partials.
// 512 threads (8 waves), tile 128o x 128w; wave = 64o x 32w (4ms x 2ns).
// Weights DIRECT from L2 to registers (no LDS). One barrier total.
// grid (16,32) -> 2 blocks/CU.
// ---------------------------------------------------------------------------
__global__ __launch_bounds__(512, 4) void conv1_mfma(
    const float* __restrict__ x, const short* __restrict__ wp1,
    const float* __restrict__ bias, const float* __restrict__ g,
    const float* __restrict__ be, const float* __restrict__ rm,
    const float* __restrict__ rv, const float* __restrict__ racc1,
    const float* __restrict__ fcb, const float* __restrict__ fcw2,
    short* __restrict__ y1p, float* __restrict__ racc2) {
  const int b = blockIdx.y;
  const int w0 = blockIdx.x * 128;
  const int tid = threadIdx.x;
  const int wave = tid >> 6, lane = tid & 63;
  const int ln = lane & 15, kg = lane >> 4;
  const int oh = wave & 1, wq = wave >> 1;

  __shared__ short xs[8 * 130 * 8];      // 16.6 KB, [ig][p][e]
  __shared__ float red[512];             // 2 KB

  // stage x tile (fp32 -> bf16), halo of 1
  const float* xb = x + (size_t)b * 64 * WLEN;
  for (int idx = tid; idx < 8 * 130; idx += 512) {
    int ig = idx / 130;
    int p = idx - ig * 130;
    int w = w0 - 1 + p;
    short8 v = {0, 0, 0, 0, 0, 0, 0, 0};
    if ((unsigned)w < (unsigned)WLEN) {
      const float* src = xb + (size_t)(ig * 8) * WLEN + w;
#pragma unroll
      for (int e = 0; e < 8; ++e) v[e] = f2bf(src[(size_t)e * WLEN]);
    }
    *(short8*)(xs + idx * 8) = v;
  }
  __syncthreads();

  floatx4 acc[4][2];
#pragma unroll
  for (int ms = 0; ms < 4; ++ms)
#pragma unroll
    for (int ns = 0; ns < 2; ++ns) acc[ms][ns] = (floatx4){0.f, 0.f, 0.f, 0.f};

#pragma unroll
  for (int q = 0; q < 2; ++q) {
#pragma unroll
    for (int k = 0; k < 3; ++k) {
      short8 af[4], bf[2];
      const short* wk =
          wp1 + ((size_t)(k * 8 + q * 4 + kg) * 128 + oh * 64 + ln) * 8;
#pragma unroll
      for (int ms = 0; ms < 4; ++ms)
        af[ms] = *(const short8*)(wk + (size_t)ms * 16 * 8);
#pragma unroll
      for (int ns = 0; ns < 2; ++ns)
        bf[ns] = *(const short8*)(
            xs + ((q * 4 + kg) * 130 + wq * 32 + ns * 16 + ln + k) * 8);
#pragma unroll
      for (int ms = 0; ms < 4; ++ms)
#pragma unroll
        for (int ns = 0; ns < 2; ++ns)
          acc[ms][ns] = __builtin_amdgcn_mfma_f32_16x16x32_bf16(
              af[ms], bf[ns], acc[ms][ns], 0, 0, 0);
    }
  }

  // r1
  float zs = 0.f;
#pragma unroll
  for (int qq = 0; qq < 8; ++qq) zs += racc1[b * 8 + qq];
  float z = zs * (1.f / (float)WLEN) + fcb[0];
  float r1v = 1.f / (1.f + expf(-z));

  float rsum2 = 0.f;
#pragma unroll
  for (int ms = 0; ms < 4; ++ms) {
    const int o0 = oh * 64 + ms * 16 + kg * 4;
    float a_[4], c_[4], fw[4];
#pragma unroll
    for (int rr = 0; rr < 4; ++rr) {
      int o = o0 + rr;
      float s = g[o] * rsqrtf(rv[o] + 1e-5f);
      a_[rr] = r1v * s;
      c_[rr] = (r1v * bias[o] - rm[o]) * s + be[o];
      fw[rr] = fcw2[o];
    }
#pragma unroll
    for (int ns = 0; ns < 2; ++ns) {
      int w = w0 + wq * 32 + ns * 16 + ln;
      short pk[4];
#pragma unroll
      for (int rr = 0; rr < 4; ++rr) {
        float v = acc[ms][ns][rr] * a_[rr] + c_[rr];
        v = v >= 0.f ? v : 0.1f * v;
        rsum2 += v * fw[rr];
        pk[rr] = f2bf(v);
      }
      // pack 4 bf16 into 2 dwords; merge with kg^1 partner (o0 xor 4)
      unsigned u0 = (unsigned)(unsigned short)pk[0] |
                    ((unsigned)(unsigned short)pk[1] << 16);
      unsigned u1 = (unsigned)(unsigned short)pk[2] |
                    ((unsigned)(unsigned short)pk[3] << 16);
      unsigned p0 = __shfl_xor((int)u0, 16);
      unsigned p1 = __shfl_xor((int)u1, 16);
      if (!(kg & 1)) {
        int4 s8;
        s8.x = (int)u0; s8.y = (int)u1; s8.z = (int)p0; s8.w = (int)p1;
        // y1p layout [b][o/8][w][8]; o0 is a multiple of 8 here
        *(int4*)(y1p + ((size_t)(b * 16 + (o0 >> 3)) * WLEN + w) * 8) = s8;
      }
    }
  }
  red[tid] = rsum2;
  __syncthreads();
  for (int s = 256; s > 0; s >>= 1) {
    if (tid < s) red[tid] += red[tid + s];
    __syncthreads();
  }
  if (tid == 0) racc2[b * 16 + blockIdx.x] = red[0];
}

// ---------------------------------------------------------------------------
// conv2: y1p bf16 [b][ig16][w][8] -> out fp32 pooled (B,256,1024).
// 256 threads = 4 waves; block tile 256o x 128w; wave = 64o x 128w
// (oq = wave, 4ms x 8ns). Weights DIRECT from L2 to registers; xs staged
// once; NO barriers in the K loop. grid (16,32) = 512 blocks, 2/CU.
// ---------------------------------------------------------------------------
__global__ __launch_bounds__(256) void conv2_mfma(
    const short* __restrict__ y1p, const short* __restrict__ wp2,
    const float* __restrict__ bias, const float* __restrict__ g,
    const float* __restrict__ be, const float* __restrict__ rm,
    const float* __restrict__ rv, const float* __restrict__ racc2,
    const float* __restrict__ fcb, float* __restrict__ out) {
  const int b = blockIdx.y;
  const int w0 = blockIdx.x * 128;
  const int tid = threadIdx.x;
  const int oq = tid >> 6, lane = tid & 63;
  const int ln = lane & 15, kg = lane >> 4;

  __shared__ short xs[16 * 130 * 8];   // 33.3 KB

  // stage x tile (once)
  const short* yb = y1p + (size_t)b * 16 * WLEN * 8;
  for (int idx = tid; idx < 16 * 130; idx += 256) {
    int ig = idx / 130;
    int p = idx - ig * 130;
    int w = w0 - 1 + p;
    short8 v = {0, 0, 0, 0, 0, 0, 0, 0};
    if ((unsigned)w < (unsigned)WLEN)
      v = *(const short8*)(yb + ((size_t)ig * WLEN + w) * 8);
    *(short8*)(xs + idx * 8) = v;
  }
  __syncthreads();

  floatx4 acc[4][8];
#pragma unroll
  for (int ms = 0; ms < 4; ++ms)
#pragma unroll
    for (int ns = 0; ns < 8; ++ns) acc[ms][ns] = (floatx4){0.f, 0.f, 0.f, 0.f};

#pragma unroll
  for (int c = 0; c < 12; ++c) {
    const int q = c >> 2, kk = c & 3;          // dummy split; real below
    const int qq = c / 3, k = c % 3;
    (void)q; (void)kk;

    short8 af[4], bf[8];
    const short* wk =
        wp2 + ((size_t)(k * 16 + qq * 4 + kg) * 256 + oq * 64 + ln) * 8;
#pragma unroll
    for (int ms = 0; ms < 4; ++ms)
      af[ms] = *(const short8*)(wk + (size_t)ms * 16 * 8);
#pragma unroll
    for (int ns = 0; ns < 8; ++ns)
      bf[ns] = *(const short8*)(
          xs + ((qq * 4 + kg) * 130 + ns * 16 + ln + k) * 8);
#pragma unroll
    for (int ms = 0; ms < 4; ++ms)
#pragma unroll
      for (int ns = 0; ns < 8; ++ns)
        acc[ms][ns] = __builtin_amdgcn_mfma_f32_16x16x32_bf16(
            af[ms], bf[ns], acc[ms][ns], 0, 0, 0);
  }

  // r2
  float zs = 0.f;
#pragma unroll
  for (int t = 0; t < 16; ++t) zs += racc2[b * 16 + t];
  float z = zs * (1.f / (float)WLEN) + fcb[0];
  float r2v = 1.f / (1.f + expf(-z));

#pragma unroll
  for (int ms = 0; ms < 4; ++ms) {
    const int o0 = oq * 64 + ms * 16 + kg * 4;
    float a_[4], c_[4];
#pragma unroll
    for (int rr = 0; rr < 4; ++rr) {
      int o = o0 + rr;
      float s = g[o] * rsqrtf(rv[o] + 1e-5f);
      a_[rr] = r2v * s;
      c_[rr] = (r2v * bias[o] - rm[o]) * s + be[o];
    }
#pragma unroll
    for (int np = 0; np < 4; ++np) {  // ns pairs (0,1),(2,3),(4,5),(6,7)
      float m0[4], m1[4];
#pragma unroll
      for (int half = 0; half < 2; ++half) {
        int ns = np * 2 + half;
#pragma unroll
        for (int rr = 0; rr < 4; ++rr) {
          float v = acc[ms][ns][rr] * a_[rr] + c_[rr];
          v = v >= 0.f ? v : 0.1f * v;
          float m = fmaxf(v, __shfl_xor(v, 1));
          if (half == 0) m0[rr] = m; else m1[rr] = m;
        }
      }
      const int pc = (w0 >> 1) + np * 16 + ln;
#pragma unroll
      for (int rr = 0; rr < 4; ++rr) {
        int src = kg * 16 + ((ln & 7) << 1);
        float aa = __shfl(m0[rr], src);
        float bb = __shfl(m1[rr], src);
        float val = (ln < 8) ? aa : bb;
        out[((size_t)(b * 256 + o0 + rr)) * (WLEN / 2) + pc] = val;
      }
    }
  }
}

// ---------------------------------------------------------------------------
extern "C" void kernel_launch(void* const* d_in, const int* in_sizes, int n_in,
                              void* d_out, int out_size, void* d_ws, size_t ws_size,
                              hipStream_t stream) {
  const float* x    = (const float*)d_in[0];
  const float* w1   = (const float*)d_in[1];
  const float* b1   = (const float*)d_in[2];
  const float* fcw1 = (const float*)d_in[3];
  const float* fcb1 = (const float*)d_in[4];
  const float* g1   = (const float*)d_in[5];
  const float* be1  = (const float*)d_in[6];
  const float* rm1  = (const float*)d_in[7];
  const float* rv1  = (const float*)d_in[8];
  const float* w2   = (const float*)d_in[9];
  const float* b2   = (const float*)d_in[10];
  const float* fcw2 = (const float*)d_in[11];
  const float* fcb2 = (const float*)d_in[12];
  const float* g2   = (const float*)d_in[13];
  const float* be2  = (const float*)d_in[14];
  const float* rm2  = (const float*)d_in[15];
  const float* rv2  = (const float*)d_in[16];
  float* out = (float*)d_out;

  char* ws = (char*)d_ws;
  short* y1p   = (short*)ws;                          // 32*16*2048*8*2 = 16 MiB
  short* wp1   = (short*)(ws + (size_t)16 * 1024 * 1024);            // 48 KiB
  short* wp2   = (short*)(ws + (size_t)16 * 1024 * 1024 + 65536);    // 192 KiB
  float* racc1 = (float*)(ws + (size_t)16 * 1024 * 1024 + 327680);   // 256 f
  float* racc2 = racc1 + 256;                                        // 512 f

  fused_prep<<<316, 256, 0, stream>>>(w1, w2, x, fcw1, wp1, wp2, racc1);
  conv1_mfma<<<dim3(16, 32), 512, 0, stream>>>(
      x, wp1, b1, g1, be1, rm1, rv1, racc1, fcb1, fcw2, y1p, racc2);
  conv2_mfma<<<dim3(16, 32), 256, 0, stream>>>(
      y1p, wp2, b2, g2, be2, rm2, rv2, racc2, fcb2, out);
}

// Round 11
// 56.079 us; speedup vs baseline: 1.7514x; 1.0719x over previous
//
#include <hip/hip_runtime.h>
#include <hip/hip_bf16.h>
#include <math.h>

#define BATCH 32
#define WLEN  2048

typedef __attribute__((ext_vector_type(8))) short short8;
typedef __attribute__((ext_vector_type(4))) short short4v;
typedef __attribute__((ext_vector_type(4))) float floatx4;

// async global->LDS DMA, 16 B per lane; lds dest must be linear in lane.
#define GLOAD_LDS16(g, l)                                                     \
  __builtin_amdgcn_global_load_lds(                                           \
      (const __attribute__((address_space(1))) unsigned int*)(g),             \
      (__attribute__((address_space(3))) unsigned int*)(l), 16, 0, 0)

__device__ inline short f2bf(float f) {
  unsigned u = __float_as_uint(f);
  unsigned r = (u + 0x7fffu + ((u >> 16) & 1u)) >> 16;
  return (short)r;
}

// ---------------------------------------------------------------------------
// fused prep: blocks 0..11 pack w1 -> wp1[k][ig8][o128][8]
//             blocks 12..59 pack w2 -> wp2[k][ig16][o256][8]
//             blocks 60..315 routing1 partials racc1[b*8+j]
// ---------------------------------------------------------------------------
__global__ __launch_bounds__(256) void fused_prep(
    const float* __restrict__ w1, const float* __restrict__ w2,
    const float* __restrict__ x, const float* __restrict__ fcw1,
    short* __restrict__ wp1, short* __restrict__ wp2,
    float* __restrict__ racc1) {
  const int blk = blockIdx.x;
  const int tid = threadIdx.x;
  if (blk < 12) {
    int iw = blk * 256 + tid;          // (k, ig, o) over 3*8*128
    int o = iw & 127;
    int t = iw >> 7;
    int ig = t & 7;
    int k = t >> 3;
    short8 v;
#pragma unroll
    for (int e = 0; e < 8; ++e) v[e] = f2bf(w1[(o * 64 + ig * 8 + e) * 3 + k]);
    *(short8*)(wp1 + (size_t)iw * 8) = v;
  } else if (blk < 60) {
    int iw = (blk - 12) * 256 + tid;   // (k, ig, o) over 3*16*256
    int o = iw & 255;
    int t = iw >> 8;
    int ig = t & 15;
    int k = t >> 4;
    short8 v;
#pragma unroll
    for (int e = 0; e < 8; ++e) v[e] = f2bf(w2[(o * 128 + ig * 8 + e) * 3 + k]);
    *(short8*)(wp2 + (size_t)iw * 8) = v;
  } else {
    int t = blk - 60;
    int j = t & 7, b = t >> 3;
    const float4* xb = (const float4*)(x + ((size_t)b * 64 + j * 8) * WLEN);
    float sum = 0.f;
    for (int idx = tid; idx < 8 * 512; idx += 256) {
      int c = idx >> 9;
      float4 v = xb[idx];
      sum += (v.x + v.y + v.z + v.w) * fcw1[j * 8 + c];
    }
    __shared__ float red[256];
    red[tid] = sum;
    __syncthreads();
    for (int s = 128; s > 0; s >>= 1) {
      if (tid < s) red[tid] += red[tid + s];
      __syncthreads();
    }
    if (tid == 0) racc1[b * 8 + j] = red[0];
  }
}

// ---------------------------------------------------------------------------
// conv1: x fp32 (B,64,W) -> y1p bf16 [b][o/8][w][8], + routing2 partials.
// 512 threads (8 waves), tile 128o x 128w; wave = 64o x 32w (4ms x 2ns).
// Weights DIRECT from L2 to registers. grid (16,32).
// ---------------------------------------------------------------------------
__global__ __launch_bounds__(512, 4) void conv1_mfma(
    const float* __restrict__ x, const short* __restrict__ wp1,
    const float* __restrict__ bias, const float* __restrict__ g,
    const float* __restrict__ be, const float* __restrict__ rm,
    const float* __restrict__ rv, const float* __restrict__ racc1,
    const float* __restrict__ fcb, const float* __restrict__ fcw2,
    short* __restrict__ y1p, float* __restrict__ racc2) {
  const int b = blockIdx.y;
  const int w0 = blockIdx.x * 128;
  const int tid = threadIdx.x;
  const int wave = tid >> 6, lane = tid & 63;
  const int ln = lane & 15, kg = lane >> 4;
  const int oh = wave & 1, wq = wave >> 1;

  __shared__ short xs[8 * 130 * 8];      // 16.6 KB, [ig][p][e]
  __shared__ float red[512];             // 2 KB

  // stage x tile (fp32 -> bf16), halo of 1
  const float* xb = x + (size_t)b * 64 * WLEN;
  for (int idx = tid; idx < 8 * 130; idx += 512) {
    int ig = idx / 130;
    int p = idx - ig * 130;
    int w = w0 - 1 + p;
    short8 v = {0, 0, 0, 0, 0, 0, 0, 0};
    if ((unsigned)w < (unsigned)WLEN) {
      const float* src = xb + (size_t)(ig * 8) * WLEN + w;
#pragma unroll
      for (int e = 0; e < 8; ++e) v[e] = f2bf(src[(size_t)e * WLEN]);
    }
    *(short8*)(xs + idx * 8) = v;
  }
  __syncthreads();

  floatx4 acc[4][2];
#pragma unroll
  for (int ms = 0; ms < 4; ++ms)
#pragma unroll
    for (int ns = 0; ns < 2; ++ns) acc[ms][ns] = (floatx4){0.f, 0.f, 0.f, 0.f};

#pragma unroll
  for (int q = 0; q < 2; ++q) {
#pragma unroll
    for (int k = 0; k < 3; ++k) {
      short8 af[4], bf[2];
      const short* wk =
          wp1 + ((size_t)(k * 8 + q * 4 + kg) * 128 + oh * 64 + ln) * 8;
#pragma unroll
      for (int ms = 0; ms < 4; ++ms)
        af[ms] = *(const short8*)(wk + (size_t)ms * 16 * 8);
#pragma unroll
      for (int ns = 0; ns < 2; ++ns)
        bf[ns] = *(const short8*)(
            xs + ((q * 4 + kg) * 130 + wq * 32 + ns * 16 + ln + k) * 8);
#pragma unroll
      for (int ms = 0; ms < 4; ++ms)
#pragma unroll
        for (int ns = 0; ns < 2; ++ns)
          acc[ms][ns] = __builtin_amdgcn_mfma_f32_16x16x32_bf16(
              af[ms], bf[ns], acc[ms][ns], 0, 0, 0);
    }
  }

  // r1
  float zs = 0.f;
#pragma unroll
  for (int qq = 0; qq < 8; ++qq) zs += racc1[b * 8 + qq];
  float z = zs * (1.f / (float)WLEN) + fcb[0];
  float r1v = 1.f / (1.f + expf(-z));

  float rsum2 = 0.f;
#pragma unroll
  for (int ms = 0; ms < 4; ++ms) {
    const int o0 = oh * 64 + ms * 16 + kg * 4;
    float a_[4], c_[4], fw[4];
#pragma unroll
    for (int rr = 0; rr < 4; ++rr) {
      int o = o0 + rr;
      float s = g[o] * rsqrtf(rv[o] + 1e-5f);
      a_[rr] = r1v * s;
      c_[rr] = (r1v * bias[o] - rm[o]) * s + be[o];
      fw[rr] = fcw2[o];
    }
#pragma unroll
    for (int ns = 0; ns < 2; ++ns) {
      int w = w0 + wq * 32 + ns * 16 + ln;
      short pk[4];
#pragma unroll
      for (int rr = 0; rr < 4; ++rr) {
        float v = acc[ms][ns][rr] * a_[rr] + c_[rr];
        v = v >= 0.f ? v : 0.1f * v;
        rsum2 += v * fw[rr];
        pk[rr] = f2bf(v);
      }
      // pack 4 bf16 into 2 dwords; merge with kg^1 partner (o0 xor 4)
      unsigned u0 = (unsigned)(unsigned short)pk[0] |
                    ((unsigned)(unsigned short)pk[1] << 16);
      unsigned u1 = (unsigned)(unsigned short)pk[2] |
                    ((unsigned)(unsigned short)pk[3] << 16);
      unsigned p0 = __shfl_xor((int)u0, 16);
      unsigned p1 = __shfl_xor((int)u1, 16);
      if (!(kg & 1)) {
        int4 s8;
        s8.x = (int)u0; s8.y = (int)u1; s8.z = (int)p0; s8.w = (int)p1;
        // y1p layout [b][o/8][w][8]; o0 is a multiple of 8 here
        *(int4*)(y1p + ((size_t)(b * 16 + (o0 >> 3)) * WLEN + w) * 8) = s8;
      }
    }
  }
  red[tid] = rsum2;
  __syncthreads();
  for (int s = 256; s > 0; s >>= 1) {
    if (tid < s) red[tid] += red[tid + s];
    __syncthreads();
  }
  if (tid == 0) racc2[b * 16 + blockIdx.x] = red[0];
}

// ---------------------------------------------------------------------------
// conv2: y1p bf16 [b][ig16][w][8] -> out fp32 pooled (B,256,1024).
// 256 threads = 4 waves (wave = oq quadrant, 64o x 64w as 2 sub-tiles of 32w).
// Both sub-tiles DMA'd to LDS up front (one drain); weights direct from L2;
// NO barriers in K loop. grid (32,32) = 1024 blocks -> 4 blocks/CU resident
// = 16 waves/CU. VGPR<=128 via launch_bounds.
// ---------------------------------------------------------------------------
__global__ __launch_bounds__(256, 4) void conv2_mfma(
    const short* __restrict__ y1p, const short* __restrict__ wp2,
    const float* __restrict__ bias, const float* __restrict__ g,
    const float* __restrict__ be, const float* __restrict__ rm,
    const float* __restrict__ rv, const float* __restrict__ racc2,
    const float* __restrict__ fcb, float* __restrict__ out) {
  const int b = blockIdx.y;
  const int w0 = blockIdx.x * 64;
  const int tid = threadIdx.x;
  const int oq = tid >> 6, lane = tid & 63;
  const int ln = lane & 15, kg = lane >> 4;

  // xs[u][ig][p] with p padded to 36 (items 16*36=576 = 2*256 + 64)
  __shared__ short8 xs8[2][576];   // 18.4 KB
  short* xs[2] = {(short*)xs8[0], (short*)xs8[1]};

  // DMA both sub-tiles (p in [0,35], w = w0 + u*32 - 1 + p; only p<=33 used)
  const short* yb = y1p + (size_t)b * 16 * WLEN * 8;
#pragma unroll
  for (int u = 0; u < 2; ++u) {
    const int wu = w0 + u * 32 - 1;
#pragma unroll
    for (int base = 0; base < 512; base += 256) {
      int idx = base + tid;
      int ig = idx / 36, p = idx - (idx / 36) * 36;
      GLOAD_LDS16(yb + ((size_t)ig * WLEN + (wu + p)) * 8,
                  (short*)xs8[u] + (size_t)idx * 8);
    }
    if (tid < 64) {
      int idx = 512 + tid;
      int ig = idx / 36, p = idx - (idx / 36) * 36;
      GLOAD_LDS16(yb + ((size_t)ig * WLEN + (wu + p)) * 8,
                  (short*)xs8[u] + (size_t)idx * 8);
    }
  }
  __syncthreads();  // drains DMA (vmcnt 0) + barrier

  // edge halo zero-fix
  if (blockIdx.x == 0 && tid < 16)
    *(short8*)((short*)xs8[0] + (size_t)(tid * 36 + 0) * 8) = (short8){0,0,0,0,0,0,0,0};
  if (blockIdx.x == 31 && tid >= 64 && tid < 80)
    *(short8*)((short*)xs8[1] + (size_t)((tid - 64) * 36 + 33) * 8) = (short8){0,0,0,0,0,0,0,0};
  __syncthreads();

  floatx4 acc[4][2][2];  // [ms][u][ns]
#pragma unroll
  for (int ms = 0; ms < 4; ++ms)
#pragma unroll
    for (int u = 0; u < 2; ++u)
#pragma unroll
      for (int ns = 0; ns < 2; ++ns) acc[ms][u][ns] = (floatx4){0.f, 0.f, 0.f, 0.f};

#pragma unroll
  for (int c = 0; c < 12; ++c) {
    const int qq = c / 3, k = c % 3;

    short8 af[4];
    const short* wk =
        wp2 + ((size_t)(k * 16 + qq * 4 + kg) * 256 + oq * 64 + ln) * 8;
#pragma unroll
    for (int ms = 0; ms < 4; ++ms)
      af[ms] = *(const short8*)(wk + (size_t)ms * 16 * 8);

    short8 bf[2][2];
#pragma unroll
    for (int u = 0; u < 2; ++u)
#pragma unroll
      for (int ns = 0; ns < 2; ++ns)
        bf[u][ns] = *(const short8*)(
            (short*)xs8[u] + (size_t)((qq * 4 + kg) * 36 + ns * 16 + ln + k) * 8);

#pragma unroll
    for (int ms = 0; ms < 4; ++ms)
#pragma unroll
      for (int u = 0; u < 2; ++u)
#pragma unroll
        for (int ns = 0; ns < 2; ++ns)
          acc[ms][u][ns] = __builtin_amdgcn_mfma_f32_16x16x32_bf16(
              af[ms], bf[u][ns], acc[ms][u][ns], 0, 0, 0);
  }

  // r2
  float zs = 0.f;
#pragma unroll
  for (int t = 0; t < 16; ++t) zs += racc2[b * 16 + t];
  float z = zs * (1.f / (float)WLEN) + fcb[0];
  float r2v = 1.f / (1.f + expf(-z));

#pragma unroll
  for (int ms = 0; ms < 4; ++ms) {
    const int o0 = oq * 64 + ms * 16 + kg * 4;
    float a_[4], c_[4];
#pragma unroll
    for (int rr = 0; rr < 4; ++rr) {
      int o = o0 + rr;
      float s = g[o] * rsqrtf(rv[o] + 1e-5f);
      a_[rr] = r2v * s;
      c_[rr] = (r2v * bias[o] - rm[o]) * s + be[o];
    }
#pragma unroll
    for (int u = 0; u < 2; ++u) {
      float m0[4], m1[4];
#pragma unroll
      for (int half = 0; half < 2; ++half) {
#pragma unroll
        for (int rr = 0; rr < 4; ++rr) {
          float v = acc[ms][u][half][rr] * a_[rr] + c_[rr];
          v = v >= 0.f ? v : 0.1f * v;
          float m = fmaxf(v, __shfl_xor(v, 1));
          if (half == 0) m0[rr] = m; else m1[rr] = m;
        }
      }
      const int pc = (w0 >> 1) + u * 16 + ln;
#pragma unroll
      for (int rr = 0; rr < 4; ++rr) {
        int src = kg * 16 + ((ln & 7) << 1);
        float aa = __shfl(m0[rr], src);
        float bb = __shfl(m1[rr], src);
        float val = (ln < 8) ? aa : bb;
        out[((size_t)(b * 256 + o0 + rr)) * (WLEN / 2) + pc] = val;
      }
    }
  }
}

// ---------------------------------------------------------------------------
extern "C" void kernel_launch(void* const* d_in, const int* in_sizes, int n_in,
                              void* d_out, int out_size, void* d_ws, size_t ws_size,
                              hipStream_t stream) {
  const float* x    = (const float*)d_in[0];
  const float* w1   = (const float*)d_in[1];
  const float* b1   = (const float*)d_in[2];
  const float* fcw1 = (const float*)d_in[3];
  const float* fcb1 = (const float*)d_in[4];
  const float* g1   = (const float*)d_in[5];
  const float* be1  = (const float*)d_in[6];
  const float* rm1  = (const float*)d_in[7];
  const float* rv1  = (const float*)d_in[8];
  const float* w2   = (const float*)d_in[9];
  const float* b2   = (const float*)d_in[10];
  const float* fcw2 = (const float*)d_in[11];
  const float* fcb2 = (const float*)d_in[12];
  const float* g2   = (const float*)d_in[13];
  const float* be2  = (const float*)d_in[14];
  const float* rm2  = (const float*)d_in[15];
  const float* rv2  = (const float*)d_in[16];
  float* out = (float*)d_out;

  char* ws = (char*)d_ws;
  // y1p offset +4 KiB so the w=-1 halo DMA read stays inside d_ws.
  short* y1p   = (short*)(ws + 4096);                       // 16 MiB
  short* wp1   = (short*)(ws + 4096 + (size_t)16 * 1024 * 1024);          // 48 KiB
  short* wp2   = (short*)(ws + 4096 + (size_t)16 * 1024 * 1024 + 65536);  // 192 KiB
  float* racc1 = (float*)(ws + (size_t)17 * 1024 * 1024);   // 256 f
  float* racc2 = racc1 + 256;                               // 512 f

  fused_prep<<<316, 256, 0, stream>>>(w1, w2, x, fcw1, wp1, wp2, racc1);
  conv1_mfma<<<dim3(16, 32), 512, 0, stream>>>(
      x, wp1, b1, g1, be1, rm1, rv1, racc1, fcb1, fcw2, y1p, racc2);
  conv2_mfma<<<dim3(32, 32), 256, 0, stream>>>(
      y1p, wp2, b2, g2, be2, rm2, rv2, racc2, fcb2, out);
}